// Round 3
// baseline (188.031 us; speedup 1.0000x reference)
//
#include <hip/hip_runtime.h>
#include <hip/hip_bf16.h>

#define EPS 1e-4f
#define NAXIS 8
#define NKNOTS 16      // interior knots; 18 total x-positions, 17 segments
#define NSEG 17
#define GRP 8          // float4-pixel-groups per thread (MLP depth)
// per-batch workspace layout (floats), stride 384:
//  [0..24)    pinv[a*3+c]
//  [24..48)   Acol[a*3+c]  (= A[c][a], transposed for axis-major access)
//  [48..56)   off[a]   = -mins[a]/dx[a]
//  [56..64)   invdx[a] = 1/dx[a]
//  [64..336)  seg[a*17+s] as float2 {coef, icept}: est = coef*f + icept
#define WS_STRIDE 384

typedef float vf4 __attribute__((ext_vector_type(4)));  // native vec: OK for nontemporal builtins

__global__ void spline_prep(const float* __restrict__ ys,
                            const float* __restrict__ A,
                            float* __restrict__ ws) {
    const int b = blockIdx.x;
    const float* Ab  = A  + (size_t)b * 3 * NAXIS;     // A[c*8+a]
    const float* ysb = ys + (size_t)b * NAXIS * NKNOTS;
    float* w = ws + (size_t)b * WS_STRIDE;
    __shared__ double Ginv[9];
    const int tid = threadIdx.x;

    if (tid == 0) {
        // G = A A^T (3x3, symmetric), fp64 for accuracy
        double G[9];
        for (int i = 0; i < 3; ++i)
            for (int j = 0; j < 3; ++j) {
                double s = 0.0;
                for (int a = 0; a < NAXIS; ++a)
                    s += (double)Ab[i * NAXIS + a] * (double)Ab[j * NAXIS + a];
                G[i * 3 + j] = s;
            }
        const double g00 = G[0], g01 = G[1], g02 = G[2];
        const double g11 = G[4], g12 = G[5], g22 = G[8];
        const double det = g00 * (g11 * g22 - g12 * g12)
                         - g01 * (g01 * g22 - g12 * g02)
                         + g02 * (g01 * g12 - g11 * g02);
        const double inv = 1.0 / det;
        Ginv[0] = (g11 * g22 - g12 * g12) * inv;
        Ginv[1] = (g02 * g12 - g01 * g22) * inv;
        Ginv[2] = (g01 * g12 - g02 * g11) * inv;
        Ginv[3] = Ginv[1];
        Ginv[4] = (g00 * g22 - g02 * g02) * inv;
        Ginv[5] = (g02 * g01 - g00 * g12) * inv;
        Ginv[6] = Ginv[2];
        Ginv[7] = Ginv[5];
        Ginv[8] = (g00 * g11 - g01 * g01) * inv;
    }
    __syncthreads();

    if (tid < 24) {                 // pinv[a][c] = sum_i A[i][a] * Ginv[i][c]
        const int a = tid / 3, c = tid % 3;
        double s = 0.0;
        for (int i = 0; i < 3; ++i)
            s += (double)Ab[i * NAXIS + a] * Ginv[i * 3 + c];
        w[a * 3 + c]      = (float)s;
        w[24 + a * 3 + c] = Ab[c * NAXIS + a];   // Acol
    }
    if (tid < NAXIS) {
        const int a = tid;
        float mn = 0.f, mx = 0.f;
        for (int c = 0; c < 3; ++c) {
            const float v = Ab[c * NAXIS + a];
            mn += (v < 0.f) ? v : 0.f;
            mx += (v > 0.f) ? v : 0.f;
        }
        const float range = mx + EPS - mn;
        const float dx = range / 17.0f;
        const float invdx = 1.0f / dx;
        w[48 + a] = -mn * invdx;     // off: idx_f = fma(f, invdx, off)
        w[56 + a] = invdx;
        float yf[NKNOTS + 2];
        yf[0] = mn;
        for (int k = 0; k < NKNOTS; ++k) yf[k + 1] = ysb[a * NKNOTS + k];
        yf[NKNOTS + 1] = mx;
        for (int s = 0; s < NSEG; ++s) {
            const float sl  = (yf[s + 1] - yf[s]) * invdx;
            const float xhi = ((float)(s + 1) / 17.0f) * range + mn;
            // est = yhi - (xhi - f)*sl  ==  sl*f + (yhi - xhi*sl)
            w[64 + (a * NSEG + s) * 2 + 0] = sl;
            w[64 + (a * NSEG + s) * 2 + 1] = yf[s + 1] - xhi * sl;
        }
    }
}

// 256 thr/block, GRP float4-triples per thread, depth-2 load pipeline.
// __launch_bounds__(256,4): 4 waves/EU -> 16 waves/CU, VGPR cap 128.
__global__ __launch_bounds__(256, 4) void spline_main(const float* __restrict__ raw,
                                                      const float* __restrict__ ws,
                                                      float* __restrict__ out,
                                                      int blocksPerBatch, int HW) {
    const int b    = blockIdx.x / blocksPerBatch;   // uniform
    const int tile = blockIdx.x % blocksPerBatch;
    const float* w = ws + (size_t)b * WS_STRIDE;    // uniform addr -> s_load

    // only the per-lane-gathered seg table goes to LDS
    __shared__ float2 sseg[NAXIS * NSEG];
    for (int i = threadIdx.x; i < NAXIS * NSEG; i += 256)
        sseg[i] = ((const float2*)(w + 64))[i];
    __syncthreads();

    const size_t pb = (size_t)b * 3 * HW;
    const int px0 = tile * (1024 * GRP) + threadIdx.x * 4;

    vf4 cr = *(const vf4*)(raw + pb + px0);
    vf4 cg = *(const vf4*)(raw + pb + HW + px0);
    vf4 cb = *(const vf4*)(raw + pb + 2 * (size_t)HW + px0);

    #pragma unroll
    for (int g = 0; g < GRP; ++g) {
        vf4 nr, ng, nb;
        if (g + 1 < GRP) {                       // prefetch next group
            const int px = px0 + (g + 1) * 1024;
            nr = *(const vf4*)(raw + pb + px);
            ng = *(const vf4*)(raw + pb + HW + px);
            nb = *(const vf4*)(raw + pb + 2 * (size_t)HW + px);
        }

        vf4 o0, o1, o2;
        #pragma unroll
        for (int p = 0; p < 4; ++p) {
            const float rc = cr[p], gc = cg[p], bc = cb[p];
            float a0 = 0.f, a1 = 0.f, a2 = 0.f;
            #pragma unroll
            for (int a = 0; a < NAXIS; ++a) {
                const float fa = fmaf(rc, w[24 + a * 3 + 0],
                                 fmaf(gc, w[24 + a * 3 + 1], bc * w[24 + a * 3 + 2]));
                const float t = fmaf(fa, w[56 + a], w[48 + a]);
                int idx = (int)t;                // trunc; t >= -eps so this floors
                idx = idx > NKNOTS ? NKNOTS : idx;
                const float2 ci = sseg[a * NSEG + idx];
                const float est = fmaf(ci.x, fa, ci.y);
                a0 = fmaf(est, w[a * 3 + 0], a0);
                a1 = fmaf(est, w[a * 3 + 1], a1);
                a2 = fmaf(est, w[a * 3 + 2], a2);
            }
            o0[p] = a0; o1[p] = a1; o2[p] = a2;
        }

        const int px = px0 + g * 1024;
        __builtin_nontemporal_store(o0, (vf4*)(out + pb + px));
        __builtin_nontemporal_store(o1, (vf4*)(out + pb + HW + px));
        __builtin_nontemporal_store(o2, (vf4*)(out + pb + 2 * (size_t)HW + px));

        cr = nr; cg = ng; cb = nb;
    }
}

extern "C" void kernel_launch(void* const* d_in, const int* in_sizes, int n_in,
                              void* d_out, int out_size, void* d_ws, size_t ws_size,
                              hipStream_t stream) {
    const float* raw = (const float*)d_in[0];
    const float* ys  = (const float*)d_in[1];
    const float* A   = (const float*)d_in[2];
    float* out = (float*)d_out;
    float* ws  = (float*)d_ws;

    const int B  = in_sizes[2] / (3 * NAXIS);        // 8
    const int HW = in_sizes[0] / (B * 3);            // 1024*1024
    const int blocksPerBatch = HW / (1024 * GRP);    // 256 thr * 4 px * GRP groups

    spline_prep<<<B, 64, 0, stream>>>(ys, A, ws);
    spline_main<<<B * blocksPerBatch, 256, 0, stream>>>(raw, ws, out, blocksPerBatch, HW);
}

// Round 4
// 187.234 us; speedup vs baseline: 1.0043x; 1.0043x over previous
//
#include <hip/hip_runtime.h>
#include <hip/hip_bf16.h>

#define EPS 1e-4f
#define NAXIS 8
#define NKNOTS 16      // interior knots; 18 total x-positions, 17 segments
#define NSEG 17
#define GRP 4          // float4-pixel-groups per thread; ALL loads issued up front
// per-batch workspace layout (floats), stride 384:
//  [0..24)    pinv[a*3+c]
//  [24..48)   Acol[a*3+c]  (= A[c][a], transposed for axis-major access)
//  [48..56)   off[a]   = -mins[a]/dx[a]
//  [56..64)   invdx[a] = 1/dx[a]
//  [64..336)  seg[a*17+s] as float2 {coef, icept}: est = coef*f + icept
#define WS_STRIDE 384

typedef float vf4 __attribute__((ext_vector_type(4)));  // native vec: OK for nontemporal builtins

__global__ void spline_prep(const float* __restrict__ ys,
                            const float* __restrict__ A,
                            float* __restrict__ ws) {
    const int b = blockIdx.x;
    const float* Ab  = A  + (size_t)b * 3 * NAXIS;     // A[c*8+a]
    const float* ysb = ys + (size_t)b * NAXIS * NKNOTS;
    float* w = ws + (size_t)b * WS_STRIDE;
    __shared__ double Ginv[9];
    const int tid = threadIdx.x;

    if (tid == 0) {
        // G = A A^T (3x3, symmetric), fp64 for accuracy
        double G[9];
        for (int i = 0; i < 3; ++i)
            for (int j = 0; j < 3; ++j) {
                double s = 0.0;
                for (int a = 0; a < NAXIS; ++a)
                    s += (double)Ab[i * NAXIS + a] * (double)Ab[j * NAXIS + a];
                G[i * 3 + j] = s;
            }
        const double g00 = G[0], g01 = G[1], g02 = G[2];
        const double g11 = G[4], g12 = G[5], g22 = G[8];
        const double det = g00 * (g11 * g22 - g12 * g12)
                         - g01 * (g01 * g22 - g12 * g02)
                         + g02 * (g01 * g12 - g11 * g02);
        const double inv = 1.0 / det;
        Ginv[0] = (g11 * g22 - g12 * g12) * inv;
        Ginv[1] = (g02 * g12 - g01 * g22) * inv;
        Ginv[2] = (g01 * g12 - g02 * g11) * inv;
        Ginv[3] = Ginv[1];
        Ginv[4] = (g00 * g22 - g02 * g02) * inv;
        Ginv[5] = (g02 * g01 - g00 * g12) * inv;
        Ginv[6] = Ginv[2];
        Ginv[7] = Ginv[5];
        Ginv[8] = (g00 * g11 - g01 * g01) * inv;
    }
    __syncthreads();

    if (tid < 24) {                 // pinv[a][c] = sum_i A[i][a] * Ginv[i][c]
        const int a = tid / 3, c = tid % 3;
        double s = 0.0;
        for (int i = 0; i < 3; ++i)
            s += (double)Ab[i * NAXIS + a] * Ginv[i * 3 + c];
        w[a * 3 + c]      = (float)s;
        w[24 + a * 3 + c] = Ab[c * NAXIS + a];   // Acol
    }
    if (tid < NAXIS) {
        const int a = tid;
        float mn = 0.f, mx = 0.f;
        for (int c = 0; c < 3; ++c) {
            const float v = Ab[c * NAXIS + a];
            mn += (v < 0.f) ? v : 0.f;
            mx += (v > 0.f) ? v : 0.f;
        }
        const float range = mx + EPS - mn;
        const float dx = range / 17.0f;
        const float invdx = 1.0f / dx;
        w[48 + a] = -mn * invdx;     // off: idx_f = fma(f, invdx, off)
        w[56 + a] = invdx;
        float yf[NKNOTS + 2];
        yf[0] = mn;
        for (int k = 0; k < NKNOTS; ++k) yf[k + 1] = ysb[a * NKNOTS + k];
        yf[NKNOTS + 1] = mx;
        for (int s = 0; s < NSEG; ++s) {
            const float sl  = (yf[s + 1] - yf[s]) * invdx;
            const float xhi = ((float)(s + 1) / 17.0f) * range + mn;
            // est = yhi - (xhi - f)*sl  ==  sl*f + (yhi - xhi*sl)
            w[64 + (a * NSEG + s) * 2 + 0] = sl;
            w[64 + (a * NSEG + s) * 2 + 1] = yf[s + 1] - xhi * sl;
        }
    }
}

// 256 thr/block, GRP float4-triples per thread.
// ALL 3*GRP loads issued before any compute -> 12 KB/wave in flight (MLP),
// consumed in issue order so the compiler emits progressive vmcnt waits.
// __launch_bounds__(256,4): VGPR cap 128 -> >=16 waves/CU.
__global__ __launch_bounds__(256, 4) void spline_main(const float* __restrict__ raw,
                                                      const float* __restrict__ ws,
                                                      float* __restrict__ out,
                                                      int blocksPerBatch, int HW) {
    const int b    = blockIdx.x / blocksPerBatch;   // uniform
    const int tile = blockIdx.x % blocksPerBatch;
    const float* w = ws + (size_t)b * WS_STRIDE;    // uniform addr -> s_load

    // only the per-lane-gathered seg table goes to LDS
    __shared__ float2 sseg[NAXIS * NSEG];
    for (int i = threadIdx.x; i < NAXIS * NSEG; i += 256)
        sseg[i] = ((const float2*)(w + 64))[i];

    const size_t pb = (size_t)b * 3 * HW;
    const int px0 = tile * (1024 * GRP) + threadIdx.x * 4;

    // ---- burst-issue all loads (oldest consumed first) ----
    vf4 R[GRP], G[GRP], Bl[GRP];
    #pragma unroll
    for (int g = 0; g < GRP; ++g) {
        const int px = px0 + g * 1024;
        R[g]  = *(const vf4*)(raw + pb + px);
        G[g]  = *(const vf4*)(raw + pb + HW + px);
        Bl[g] = *(const vf4*)(raw + pb + 2 * (size_t)HW + px);
    }
    __syncthreads();   // sseg ready (placed after load issue to keep loads early)

    #pragma unroll
    for (int g = 0; g < GRP; ++g) {
        vf4 o0, o1, o2;
        #pragma unroll
        for (int p = 0; p < 4; ++p) {
            const float rc = R[g][p], gc = G[g][p], bc = Bl[g][p];
            float a0 = 0.f, a1 = 0.f, a2 = 0.f;
            #pragma unroll
            for (int a = 0; a < NAXIS; ++a) {
                const float fa = fmaf(rc, w[24 + a * 3 + 0],
                                 fmaf(gc, w[24 + a * 3 + 1], bc * w[24 + a * 3 + 2]));
                const float t = fmaf(fa, w[56 + a], w[48 + a]);
                int idx = (int)t;                // trunc; t >= -eps so this floors
                idx = idx > NKNOTS ? NKNOTS : idx;
                const float2 ci = sseg[a * NSEG + idx];
                const float est = fmaf(ci.x, fa, ci.y);
                a0 = fmaf(est, w[a * 3 + 0], a0);
                a1 = fmaf(est, w[a * 3 + 1], a1);
                a2 = fmaf(est, w[a * 3 + 2], a2);
            }
            o0[p] = a0; o1[p] = a1; o2[p] = a2;
        }

        const int px = px0 + g * 1024;
        __builtin_nontemporal_store(o0, (vf4*)(out + pb + px));
        __builtin_nontemporal_store(o1, (vf4*)(out + pb + HW + px));
        __builtin_nontemporal_store(o2, (vf4*)(out + pb + 2 * (size_t)HW + px));
    }
}

extern "C" void kernel_launch(void* const* d_in, const int* in_sizes, int n_in,
                              void* d_out, int out_size, void* d_ws, size_t ws_size,
                              hipStream_t stream) {
    const float* raw = (const float*)d_in[0];
    const float* ys  = (const float*)d_in[1];
    const float* A   = (const float*)d_in[2];
    float* out = (float*)d_out;
    float* ws  = (float*)d_ws;

    const int B  = in_sizes[2] / (3 * NAXIS);        // 8
    const int HW = in_sizes[0] / (B * 3);            // 1024*1024
    const int blocksPerBatch = HW / (1024 * GRP);    // 256 thr * 4 px * GRP groups

    spline_prep<<<B, 64, 0, stream>>>(ys, A, ws);
    spline_main<<<B * blocksPerBatch, 256, 0, stream>>>(raw, ws, out, blocksPerBatch, HW);
}